// Round 7
// baseline (3589.451 us; speedup 1.0000x reference)
//
#include <hip/hip_runtime.h>
#include <hip/hip_bf16.h>

// GRU: V=50000, E=256, H=256, B=64, T=512
// out: outputs[T,B,H] f32 then h_last[1,B,H] f32 (concat flat)

#define T_SEQ 512
#define B_SZ 64
#define E_DIM 256
#define H_DIM 256
#define G3 768   // 3*H

typedef _Float16 half2v __attribute__((ext_vector_type(2)));
typedef _Float16 f16x8  __attribute__((ext_vector_type(8)));
typedef float    f32x4  __attribute__((ext_vector_type(4)));

#if __has_builtin(__builtin_amdgcn_fdot2)
#define FDOT2(a, b, c) __builtin_amdgcn_fdot2((a), (b), (c), false)
#else
#define FDOT2(a, b, c) ((c) + (float)(a).x * (float)(b).x + (float)(a).y * (float)(b).y)
#endif

// ---------------- Kernel 0: W_hh f32 -> f16 (once) -------------------------
__global__ __launch_bounds__(256) void convert_whh(
    const float* __restrict__ W, _Float16* __restrict__ wf)
{
    int i = blockIdx.x * 256 + threadIdx.x;   // 49152 threads, 4 elems each
    float4 v = reinterpret_cast<const float4*>(W)[i];
    half2v a{(_Float16)v.x, (_Float16)v.y};
    half2v b{(_Float16)v.z, (_Float16)v.w};
    uint2 o{__builtin_bit_cast(uint32_t, a), __builtin_bit_cast(uint32_t, b)};
    reinterpret_cast<uint2*>(wf)[i] = o;
}

// ---------------- Kernel A: x_proj via MFMA f16 ----------------------------
// C[M=T*B=32768, N=768] = gather(emb)[M,K=256] @ W_ih^T + b_ih (+ b_hh r/z).
// 128x128 tile, 256 threads = 4 waves; wave w owns rows [w*32, w*32+32).
// mfma_f32_16x16x32_f16; A-frag row = lane&15, B-frag col = lane&15,
// k-slots contiguous 8 per lane-group (self-consistent A/B slot order).
// D mapping (verified m89): row=(lane>>4)*4+i, col=lane&15.
// Output xp stored as f16.
__global__ __launch_bounds__(256) void xproj_mfma_kernel(
    const int* __restrict__ input,
    const float* __restrict__ emb,
    const float* __restrict__ W_ih,
    const float* __restrict__ b_ih,
    const float* __restrict__ b_hh,
    _Float16* __restrict__ xp)
{
    __shared__ int rowidx[128];
    __shared__ __align__(16) _Float16 Af[2][128][40];  // stride 80B (16B-mult)
    __shared__ __align__(16) _Float16 Bf[2][128][40];

    const int tid = threadIdx.x;
    const int m0 = blockIdx.x * 128;
    const int n0 = blockIdx.y * 128;
    const int w  = tid >> 6;     // wave 0..3
    const int l  = tid & 63;
    const int g  = l >> 4;       // 0..3
    const int lr = l & 15;

    if (tid < 128) {
        int m = m0 + tid;
        rowidx[tid] = input[(m & 63) * T_SEQ + (m >> 6)];
    }
    __syncthreads();

    const int srow = tid >> 1;          // 0..127
    const int sseg = tid & 1;           // 0..1 (16-float segment)

    // ---- prologue: stage k-step 0 into buffer 0 ----
    {
        const float* sa = emb + (size_t)rowidx[srow] * E_DIM + sseg * 16;
        const float* sb = W_ih + (size_t)(n0 + srow) * E_DIM + sseg * 16;
        float4 av0 = reinterpret_cast<const float4*>(sa)[0];
        float4 av1 = reinterpret_cast<const float4*>(sa)[1];
        float4 av2 = reinterpret_cast<const float4*>(sa)[2];
        float4 av3 = reinterpret_cast<const float4*>(sa)[3];
        float4 bv0 = reinterpret_cast<const float4*>(sb)[0];
        float4 bv1 = reinterpret_cast<const float4*>(sb)[1];
        float4 bv2 = reinterpret_cast<const float4*>(sb)[2];
        float4 bv3 = reinterpret_cast<const float4*>(sb)[3];
        _Float16* da = &Af[0][srow][sseg * 16];
        _Float16* db = &Bf[0][srow][sseg * 16];
        #pragma unroll
        for (int u = 0; u < 4; ++u) {
            float4 a = (u==0)?av0:(u==1)?av1:(u==2)?av2:av3;
            float4 bq = (u==0)?bv0:(u==1)?bv1:(u==2)?bv2:bv3;
            da[u*4+0]=(_Float16)a.x; da[u*4+1]=(_Float16)a.y;
            da[u*4+2]=(_Float16)a.z; da[u*4+3]=(_Float16)a.w;
            db[u*4+0]=(_Float16)bq.x; db[u*4+1]=(_Float16)bq.y;
            db[u*4+2]=(_Float16)bq.z; db[u*4+3]=(_Float16)bq.w;
        }
    }
    __syncthreads();

    f32x4 acc[2][8];
    #pragma unroll
    for (int mt = 0; mt < 2; ++mt)
        #pragma unroll
        for (int nt = 0; nt < 8; ++nt)
            acc[mt][nt] = f32x4{0.f, 0.f, 0.f, 0.f};

    int p = 0;
    for (int kk = 0; kk < 8; ++kk) {
        // issue next-tile staging loads early (latency hidden under MFMA)
        float4 av0, av1, av2, av3, bv0, bv1, bv2, bv3;
        if (kk < 7) {
            const float* sa = emb + (size_t)rowidx[srow] * E_DIM + (kk+1)*32 + sseg*16;
            const float* sb = W_ih + (size_t)(n0 + srow) * E_DIM + (kk+1)*32 + sseg*16;
            av0 = reinterpret_cast<const float4*>(sa)[0];
            av1 = reinterpret_cast<const float4*>(sa)[1];
            av2 = reinterpret_cast<const float4*>(sa)[2];
            av3 = reinterpret_cast<const float4*>(sa)[3];
            bv0 = reinterpret_cast<const float4*>(sb)[0];
            bv1 = reinterpret_cast<const float4*>(sb)[1];
            bv2 = reinterpret_cast<const float4*>(sb)[2];
            bv3 = reinterpret_cast<const float4*>(sb)[3];
        }

        // fragment reads + MFMA
        f16x8 afr[2], bfr[8];
        #pragma unroll
        for (int mt = 0; mt < 2; ++mt) {
            uint4 u = *reinterpret_cast<const uint4*>(&Af[p][w*32 + mt*16 + lr][g*8]);
            afr[mt] = __builtin_bit_cast(f16x8, u);
        }
        #pragma unroll
        for (int nt = 0; nt < 8; ++nt) {
            uint4 u = *reinterpret_cast<const uint4*>(&Bf[p][nt*16 + lr][g*8]);
            bfr[nt] = __builtin_bit_cast(f16x8, u);
        }
        #pragma unroll
        for (int mt = 0; mt < 2; ++mt)
            #pragma unroll
            for (int nt = 0; nt < 8; ++nt)
                acc[mt][nt] = __builtin_amdgcn_mfma_f32_16x16x32_f16(
                    afr[mt], bfr[nt], acc[mt][nt], 0, 0, 0);

        if (kk < 7) {
            _Float16* da = &Af[p ^ 1][srow][sseg * 16];
            _Float16* db = &Bf[p ^ 1][srow][sseg * 16];
            #pragma unroll
            for (int u = 0; u < 4; ++u) {
                float4 a = (u==0)?av0:(u==1)?av1:(u==2)?av2:av3;
                float4 bq = (u==0)?bv0:(u==1)?bv1:(u==2)?bv2:bv3;
                da[u*4+0]=(_Float16)a.x; da[u*4+1]=(_Float16)a.y;
                da[u*4+2]=(_Float16)a.z; da[u*4+3]=(_Float16)a.w;
                db[u*4+0]=(_Float16)bq.x; db[u*4+1]=(_Float16)bq.y;
                db[u*4+2]=(_Float16)bq.z; db[u*4+3]=(_Float16)bq.w;
            }
        }
        __syncthreads();
        p ^= 1;
    }

    // ---- epilogue: add bias, store f16 ----
    #pragma unroll
    for (int nt = 0; nt < 8; ++nt) {
        const int col = n0 + nt * 16 + lr;
        const float bias = b_ih[col] + (col < 512 ? b_hh[col] : 0.0f);
        #pragma unroll
        for (int mt = 0; mt < 2; ++mt) {
            const int rbase = m0 + w * 32 + mt * 16 + g * 4;
            #pragma unroll
            for (int i = 0; i < 4; ++i)
                xp[(size_t)(rbase + i) * G3 + col] = (_Float16)(acc[mt][nt][i] + bias);
        }
    }
}

// ---------------- Kernel B: GRU scan, f16 weight streaming -----------------
// 64 blocks (1/batch), 1024 threads. Thread (jj=tid>>3, q=tid&7) owns rows
// {jj+128s, s=0..5} x k-slice [32q,32q+32) of wf16, STREAMED each step
// (f16 halves the L2-roofline vs f32: ~340us). Pointers re-pinned via empty
// asm each iteration so loop-invariant loads can't be hoisted into a
// register-spilling live set (R2-R5 lesson). h broadcast via LDS; 8-lane
// shfl_xor reduce; 1 barrier/step.
__device__ __forceinline__ float fast_sigmoid(float x) {
    float e = __expf(-x);
    return __builtin_amdgcn_rcpf(1.0f + e);
}
__device__ __forceinline__ float fast_tanh(float x) {
    x = fminf(x, 8.0f);
    float e = __expf(2.0f * x);
    return (e - 1.0f) * __builtin_amdgcn_rcpf(e + 1.0f);
}

__global__ __launch_bounds__(1024) void gru_scan_kernel(
    const _Float16* __restrict__ xp,   // [T*B, 768] f16 (b_ih + r/z b_hh folded)
    const _Float16* __restrict__ wf,   // [768, 256] f16
    const float* __restrict__ b_hh,
    float* __restrict__ out)           // outputs [T*B*256] ++ h_last [64*256]
{
    const int b   = blockIdx.x;
    const int tid = threadIdx.x;
    const int jj  = tid >> 3;      // 0..127 : columns (jj, jj+128)
    const int q   = tid & 7;       // k-slice [32q, 32q+32)

    __shared__ __align__(16) _Float16 hs[2][H_DIM];

    uint64_t wp0 = (uint64_t)(wf + (size_t)(jj +   0) * H_DIM + q * 32);
    uint64_t wp1 = (uint64_t)(wf + (size_t)(jj + 128) * H_DIM + q * 32);
    uint64_t wp2 = (uint64_t)(wf + (size_t)(jj + 256) * H_DIM + q * 32);
    uint64_t wp3 = (uint64_t)(wf + (size_t)(jj + 384) * H_DIM + q * 32);
    uint64_t wp4 = (uint64_t)(wf + (size_t)(jj + 512) * H_DIM + q * 32);
    uint64_t wp5 = (uint64_t)(wf + (size_t)(jj + 640) * H_DIM + q * 32);

    const float bn0 = b_hh[512 + jj];
    const float bn1 = b_hh[512 + jj + 128];

    if (tid < 32) reinterpret_cast<uint4*>(hs[0])[tid] = uint4{0, 0, 0, 0};
    __syncthreads();

    const int c0 = jj, c1 = jj + 128;
    float h0 = 0.0f, h1 = 0.0f;

    for (int t = 0; t < T_SEQ; ++t) {
        // re-pin pointers: forces fresh loads each step (no giant hoist)
        asm volatile("" : "+v"(wp0), "+v"(wp1), "+v"(wp2),
                          "+v"(wp3), "+v"(wp4), "+v"(wp5));
        const uint4* rp[6] = {(const uint4*)wp0, (const uint4*)wp1,
                              (const uint4*)wp2, (const uint4*)wp3,
                              (const uint4*)wp4, (const uint4*)wp5};

        const _Float16* xrow = xp + ((size_t)t * B_SZ + b) * G3;
        const float xr0 = (float)xrow[c0],       xr1 = (float)xrow[c1];
        const float xz0 = (float)xrow[256 + c0], xz1 = (float)xrow[256 + c1];
        const float xn0 = (float)xrow[512 + c0], xn1 = (float)xrow[512 + c1];

        float a0 = 0.f, a1 = 0.f, a2 = 0.f, a3 = 0.f, a4 = 0.f, a5 = 0.f;

        // rolling window: slots i = c*6+s; preload 6, consume i / issue i+6
        uint4 L[24];
        #pragma unroll
        for (int i = 0; i < 6; ++i)
            L[i] = rp[i % 6][i / 6];

        #pragma unroll
        for (int c = 0; c < 4; ++c) {
            const uint4 hv = *reinterpret_cast<const uint4*>(&hs[t & 1][q * 32 + c * 8]);
            const half2v p0 = __builtin_bit_cast(half2v, hv.x);
            const half2v p1 = __builtin_bit_cast(half2v, hv.y);
            const half2v p2 = __builtin_bit_cast(half2v, hv.z);
            const half2v p3 = __builtin_bit_cast(half2v, hv.w);
            #pragma unroll
            for (int s = 0; s < 6; ++s) {
                const int i = c * 6 + s;
                if (i + 6 < 24) L[i + 6] = rp[(i + 6) % 6][(i + 6) / 6];
                const half2v w0 = __builtin_bit_cast(half2v, L[i].x);
                const half2v w1 = __builtin_bit_cast(half2v, L[i].y);
                const half2v w2 = __builtin_bit_cast(half2v, L[i].z);
                const half2v w3 = __builtin_bit_cast(half2v, L[i].w);
                float acc = (s==0)?a0:(s==1)?a1:(s==2)?a2:(s==3)?a3:(s==4)?a4:a5;
                acc = FDOT2(w0, p0, acc);
                acc = FDOT2(w1, p1, acc);
                acc = FDOT2(w2, p2, acc);
                acc = FDOT2(w3, p3, acc);
                if (s==0) a0=acc; else if (s==1) a1=acc; else if (s==2) a2=acc;
                else if (s==3) a3=acc; else if (s==4) a4=acc; else a5=acc;
            }
        }

        // 8-lane butterfly reduce within q-group
        a0 += __shfl_xor(a0, 1); a0 += __shfl_xor(a0, 2); a0 += __shfl_xor(a0, 4);
        a1 += __shfl_xor(a1, 1); a1 += __shfl_xor(a1, 2); a1 += __shfl_xor(a1, 4);
        a2 += __shfl_xor(a2, 1); a2 += __shfl_xor(a2, 2); a2 += __shfl_xor(a2, 4);
        a3 += __shfl_xor(a3, 1); a3 += __shfl_xor(a3, 2); a3 += __shfl_xor(a3, 4);
        a4 += __shfl_xor(a4, 1); a4 += __shfl_xor(a4, 2); a4 += __shfl_xor(a4, 4);
        a5 += __shfl_xor(a5, 1); a5 += __shfl_xor(a5, 2); a5 += __shfl_xor(a5, 4);

        const float r0 = fast_sigmoid(xr0 + a0);
        const float r1 = fast_sigmoid(xr1 + a1);
        const float z0 = fast_sigmoid(xz0 + a2);
        const float z1 = fast_sigmoid(xz1 + a3);
        const float n0 = fast_tanh(xn0 + r0 * (a4 + bn0));
        const float n1 = fast_tanh(xn1 + r1 * (a5 + bn1));
        h0 = (1.0f - z0) * n0 + z0 * h0;
        h1 = (1.0f - z1) * n1 + z1 * h1;

        if (q == 0) {
            float* orow = out + ((size_t)t * B_SZ + b) * H_DIM;
            orow[c0] = h0;
            orow[c1] = h1;
            hs[(t + 1) & 1][c0] = (_Float16)h0;
            hs[(t + 1) & 1][c1] = (_Float16)h1;
        }
        __syncthreads();
    }

    if (q == 0) {
        float* hl = out + (size_t)T_SEQ * B_SZ * H_DIM + (size_t)b * H_DIM;
        hl[c0] = h0;
        hl[c1] = h1;
    }
}

extern "C" void kernel_launch(void* const* d_in, const int* in_sizes, int n_in,
                              void* d_out, int out_size, void* d_ws, size_t ws_size,
                              hipStream_t stream) {
    const int*   input = (const int*)d_in[0];
    const float* emb   = (const float*)d_in[1];
    const float* W_ih  = (const float*)d_in[2];
    const float* W_hh  = (const float*)d_in[3];
    const float* b_ih  = (const float*)d_in[4];
    const float* b_hh  = (const float*)d_in[5];
    float* out = (float*)d_out;

    _Float16* xp   = (_Float16*)d_ws;                       // 50,331,648 B
    _Float16* wf16 = (_Float16*)((char*)d_ws + 50331648);   // 393,216 B

    convert_whh<<<192, 256, 0, stream>>>(W_hh, wf16);

    dim3 gridA(T_SEQ * B_SZ / 128, G3 / 128);   // (256, 6)
    xproj_mfma_kernel<<<gridA, 256, 0, stream>>>(input, emb, W_ih, b_ih, b_hh, xp);

    gru_scan_kernel<<<B_SZ, 1024, 0, stream>>>(xp, wf16, b_hh, out);
}